// Round 3
// baseline (35.741 us; speedup 1.0000x reference)
//
#include <hip/hip_runtime.h>
#include <math.h>

// B=4, T=S=512, M=N=512, H=128
#define KDIM 512
#define HDIM 128
#define SDIM 512
#define INV_SCALE 0.04419417382415922f   // 1/sqrt(512)

// score[b,t,s] = a'[b,t] + c'[b,s],
//   a'[b,t] = inv_scale * sum_h v[h]    * tanh(q[b,t,:]·W2[h,:])
//   c'[b,s] = inv_scale * sum_h v[H+h]  * tanh(k[b,s,:]·W1[h,:])

__device__ __forceinline__ float fast_tanh(float x) {
    // tanh(x) = 1 - 2/(e^{2x}+1); ~1e-7 abs error, graceful at +/-inf
    float e = __expf(2.0f * x);
    return 1.0f - 2.0f / (e + 1.0f);
}

// 512 threads: computes sm_a[r] = INV_SCALE * sum_h vv[h]*tanh(X[row0+r,:]·W[h,:]), r=0..7.
// Thread layout: ks = tid&31 (K-split, lane bits 0-4), hg = tid>>5 (16 groups of 8 h).
__device__ __forceinline__ void proj8(
    const float* __restrict__ X, const float* __restrict__ W,
    const float* __restrict__ vv, int row0,
    float (&sm_x)[8][KDIM], float (&sm_p)[8][8], float (&sm_a)[8])
{
    const int tid = threadIdx.x;
    const int ks  = tid & 31;
    const int hg  = tid >> 5;   // 0..15

    // Stage X tile: 8*512 floats = 1024 float4; 2 per thread, coalesced.
    {
        const float4* __restrict__ src = (const float4*)(X + (size_t)row0 * KDIM);
        float4* dst = (float4*)(&sm_x[0][0]);
        dst[tid]       = src[tid];
        dst[tid + 512] = src[tid + 512];
    }
    __syncthreads();

    float acc[8][8];
    #pragma unroll
    for (int r = 0; r < 8; ++r)
        #pragma unroll
        for (int h = 0; h < 8; ++h) acc[r][h] = 0.0f;

    const float* __restrict__ wbase = W + (size_t)(hg * 8) * KDIM;

    // Thread covers K cols {jj*128 + ks*4 .. +3}, jj=0..3 (16 of 512 cols).
    // Per jj: 8 W float4 loads (1KB/wave, coalesced) + 8 LDS b128 reads + 256 FMAs.
    #pragma unroll 2
    for (int jj = 0; jj < 4; ++jj) {
        const int col = jj * 128 + ks * 4;
        float4 w[8];
        #pragma unroll
        for (int h = 0; h < 8; ++h)
            w[h] = *(const float4*)(wbase + h * KDIM + col);
        #pragma unroll
        for (int r = 0; r < 8; ++r) {
            const float4 x = *(const float4*)(&sm_x[r][col]);
            #pragma unroll
            for (int h = 0; h < 8; ++h) {
                acc[r][h] = fmaf(x.x, w[h].x, acc[r][h]);
                acc[r][h] = fmaf(x.y, w[h].y, acc[r][h]);
                acc[r][h] = fmaf(x.z, w[h].z, acc[r][h]);
                acc[r][h] = fmaf(x.w, w[h].w, acc[r][h]);
            }
        }
    }

    // K-split reduce over ks (lane bits 0-4): all lanes end with full dots.
    #pragma unroll
    for (int r = 0; r < 8; ++r)
        #pragma unroll
        for (int h = 0; h < 8; ++h) {
            float s = acc[r][h];
            s += __shfl_xor(s, 1, 64);
            s += __shfl_xor(s, 2, 64);
            s += __shfl_xor(s, 4, 64);
            s += __shfl_xor(s, 8, 64);
            s += __shfl_xor(s, 16, 64);
            acc[r][h] = s;
        }

    const float4 v0 = *(const float4*)(vv + hg * 8);
    const float4 v1 = *(const float4*)(vv + hg * 8 + 4);

    const int wave = tid >> 6;
    const int lane = tid & 63;
    #pragma unroll
    for (int r = 0; r < 8; ++r) {
        float rs = v0.x * fast_tanh(acc[r][0]) + v0.y * fast_tanh(acc[r][1])
                 + v0.z * fast_tanh(acc[r][2]) + v0.w * fast_tanh(acc[r][3])
                 + v1.x * fast_tanh(acc[r][4]) + v1.y * fast_tanh(acc[r][5])
                 + v1.z * fast_tanh(acc[r][6]) + v1.w * fast_tanh(acc[r][7]);
        // combine the wave's two hg values (lane bit 5)
        rs += __shfl_xor(rs, 32, 64);
        if (lane == 0) sm_p[wave][r] = rs;
    }
    __syncthreads();

    if (tid < 8) {
        float s = 0.0f;
        #pragma unroll
        for (int w = 0; w < 8; ++w) s += sm_p[w][tid];
        sm_a[tid] = s * INV_SCALE;
    }
    __syncthreads();
}

__global__ __launch_bounds__(512, 2) void keys_kernel(
    const float* __restrict__ keys, const float* __restrict__ W1,
    const float* __restrict__ v, float* __restrict__ cproj)
{
    __shared__ float sm_x[8][KDIM];
    __shared__ float sm_p[8][8];
    __shared__ float sm_a[8];
    const int row0 = blockIdx.x * 8;   // global bs row
    proj8(keys, W1, v + HDIM, row0, sm_x, sm_p, sm_a);
    if (threadIdx.x < 8) cproj[row0 + threadIdx.x] = sm_a[threadIdx.x];
}

__global__ __launch_bounds__(512, 2) void query_out_kernel(
    const float* __restrict__ query, const float* __restrict__ W2,
    const float* __restrict__ v, const float* __restrict__ cproj,
    float* __restrict__ out)
{
    __shared__ float sm_x[8][KDIM];
    __shared__ float sm_p[8][8];
    __shared__ float sm_a[8];
    const int row0 = blockIdx.x * 8;   // global bt row
    const int lane = threadIdx.x & 63;
    const int wave = threadIdx.x >> 6;
    const int b = row0 >> 9;

    // Prefetch this block's c' slice early (hides cross-kernel L2/L3 latency).
    const float4 c0 = *(const float4*)(cproj + b * SDIM + lane * 8);
    const float4 c1 = *(const float4*)(cproj + b * SDIM + lane * 8 + 4);

    proj8(query, W2, v, row0, sm_x, sm_p, sm_a);

    // wave w owns output row (row0 + w); lanes cover S via 2x float4.
    const float a = sm_a[wave];
    float4 o0, o1;
    o0.x = a + c0.x; o0.y = a + c0.y; o0.z = a + c0.z; o0.w = a + c0.w;
    o1.x = a + c1.x; o1.y = a + c1.y; o1.z = a + c1.z; o1.w = a + c1.w;
    float4* __restrict__ op = (float4*)(out + (size_t)(row0 + wave) * SDIM + lane * 8);
    op[0] = o0;
    op[1] = o1;
}

extern "C" void kernel_launch(void* const* d_in, const int* in_sizes, int n_in,
                              void* d_out, int out_size, void* d_ws, size_t ws_size,
                              hipStream_t stream) {
    const float* query = (const float*)d_in[0];  // (4,512,512)
    const float* keys  = (const float*)d_in[1];  // (4,512,512)
    const float* W1    = (const float*)d_in[2];  // (128,512)
    const float* W2    = (const float*)d_in[3];  // (128,512)
    const float* v     = (const float*)d_in[4];  // (1,256)
    float* out = (float*)d_out;                  // (4,512,512) f32
    float* ws  = (float*)d_ws;                   // c' needs 2048 floats

    keys_kernel<<<256, 512, 0, stream>>>(keys, W1, v, ws);
    query_out_kernel<<<256, 512, 0, stream>>>(query, W2, v, ws, out);
}